// Round 12
// baseline (498.513 us; speedup 1.0000x reference)
//
#include <hip/hip_runtime.h>
#include <hip/hip_bf16.h>

// Glm4MoeExpertLayers: x[T,H] fp32, Wgu[E,2I,H] fp32, Wdn[E,H,I] fp32, expert_idx
//   gu = x @ Wgu[e]^T ; hidden = silu(gu[:, :I]) * gu[:, I:] ; out = hidden @ Wdn[e]^T
// T=16384 H=2048 I=1536.
// R12 = R10 (128^2 two-barrier, 16x16x32 MFMA, proven conflict-free B swizzle)
// + A-fragments loaded global->register (LDS bypass): R10 was DS-pipe-bound
// (96KB reads/block-K-tile ~ 1156cyc > MFMA 1242cyc serial). LDS now carries
// only B (GEMM1: Bg+Bu 32KB; GEMM2: B 16KB) -> DS ~700cyc < MFMA.
// A-panel reuse is L2-local (XCD swizzle groups same-panel blocks).
// R11 lesson: 32x32 frag reads re-conflict (1.9e7); 16x16 pattern stays 0.

namespace {

constexpr int T_ = 16384;
constexpr int H_ = 2048;
constexpr int I_ = 1536;

typedef short short8 __attribute__((ext_vector_type(8)));
typedef float f32x4 __attribute__((ext_vector_type(4)));
typedef unsigned short ushort4v __attribute__((ext_vector_type(4)));

__device__ __forceinline__ unsigned short f2bf(float f) {
    union { float f; unsigned u; } v; v.f = f;
    return (unsigned short)((v.u + 0x7FFFu + ((v.u >> 16) & 1u)) >> 16);
}

typedef __attribute__((address_space(1))) const void gvoid;
typedef __attribute__((address_space(3))) void lvoid;
__device__ __forceinline__ void gload16(const void* g, void* l) {
    __builtin_amdgcn_global_load_lds((gvoid*)g, (lvoid*)l, 16, 0, 0);
}

// ---------------------------------------------------------------------------
// fused fp32->bf16 conversion of x, Wgu[e], Wdn[e]
// ---------------------------------------------------------------------------
__global__ void k_cvt_all(const float* __restrict__ x, const float* __restrict__ wgu,
                          const float* __restrict__ wdn, const int* __restrict__ eidx,
                          unsigned short* __restrict__ xb, unsigned short* __restrict__ wgub,
                          unsigned short* __restrict__ wdnb) {
    const int e = *eidx;
    const int n1 = T_ * H_ / 4;
    const int n2 = 2 * I_ * H_ / 4;
    const int n3 = H_ * I_ / 4;
    const int ntot = n1 + n2 + n3;
    const float* wgu_e = wgu + (size_t)e * (size_t)(2 * I_) * H_;
    const float* wdn_e = wdn + (size_t)e * (size_t)H_ * I_;
    const int stride = gridDim.x * blockDim.x;
    for (int i = blockIdx.x * blockDim.x + threadIdx.x; i < ntot; i += stride) {
        const float* src; unsigned short* dst; int j;
        if (i < n1)           { src = x;     dst = xb;   j = i; }
        else if (i < n1 + n2) { src = wgu_e; dst = wgub; j = i - n1; }
        else                  { src = wdn_e; dst = wdnb; j = i - n1 - n2; }
        f32x4 v = ((const f32x4*)src)[j];
        ushort4v h = { f2bf(v[0]), f2bf(v[1]), f2bf(v[2]), f2bf(v[3]) };
        ((ushort4v*)dst)[j] = h;
    }
}

// ---------------------------------------------------------------------------
// GEMM1 + SwiGLU: hidden[T,I](bf16) = silu(xb@Wg^T) * (xb@Wu^T)
// 256 thr (4 waves 2x2), tile 128x128, BK=64 over H, dual-B in-wave.
// A: global->register fragments (L2-served, no LDS).
// B: gload_lds staged, [128 rows][8 slots 16B], slot ^= row&7 (both-sides).
// ---------------------------------------------------------------------------
__global__ __launch_bounds__(256, 2) void k_gemm1_swiglu(
    const unsigned short* __restrict__ xb, const unsigned short* __restrict__ wgub,
    unsigned short* __restrict__ hidden)
{
    __shared__ unsigned short lds[2 * 128 * 64];   // Bg | Bu
    unsigned short* ldsBg = lds;
    unsigned short* ldsBu = lds + 128 * 64;

    const int tid  = threadIdx.x;
    const int lane = tid & 63;
    const int wv   = tid >> 6;
    const int wr   = wv >> 1, wc = wv & 1;

    // XCD-aware bijective swizzle over 1536 blocks (1536 % 8 == 0)
    const int nb = (blockIdx.x & 7) * 192 + (blockIdx.x >> 3);
    const int bx = nb % 12, by = nb / 12;
    const int m0 = by * 128;
    const int n0 = bx * 128;

    f32x4 accG[4][4], accU[4][4];
    #pragma unroll
    for (int a = 0; a < 4; ++a)
        #pragma unroll
        for (int b = 0; b < 4; ++b) { accG[a][b] = (f32x4)0.0f; accU[a][b] = (f32x4)0.0f; }

    const int drow = lane >> 3;                   // staging row (== row & 7)
    const int gcol = (((lane & 7) ^ drow) * 8);   // pre-swizzled source col (bf16)
    const int l15 = lane & 15;
    const int l4  = lane >> 4;
    const int sw  = l15 & 7;

    // per-lane A base: row = m0 + wr*64 + a*16 + l15 ; col = k0 + kk*32 + l4*8
    const unsigned short* aBase = xb + (size_t)(m0 + wr * 64 + l15) * H_ + l4 * 8;

    for (int k0 = 0; k0 < H_; k0 += 64) {
        __syncthreads();
        // A fragments: 8 global 16B loads (both kk), overlap with B staging
        short8 af[2][4];
        #pragma unroll
        for (int kk = 0; kk < 2; ++kk)
            #pragma unroll
            for (int a = 0; a < 4; ++a)
                af[kk][a] = *(const short8*)(aBase + (size_t)(a * 16) * H_ + k0 + kk * 32);
        // B staging (async DMA)
        #pragma unroll
        for (int r = 0; r < 4; ++r) {
            const int row  = r * 32 + wv * 8 + drow;
            const int loff = r * 2048 + wv * 512;
            gload16(wgub + (size_t)(n0 + row)      * H_ + k0 + gcol, ldsBg + loff);
            gload16(wgub + (size_t)(I_ + n0 + row) * H_ + k0 + gcol, ldsBu + loff);
        }
        __syncthreads();

        #pragma unroll
        for (int kk = 0; kk < 2; ++kk) {
            const int sl = ((kk * 4 + l4) ^ sw) * 8;
            short8 bg[4], bu[4];
            #pragma unroll
            for (int b = 0; b < 4; ++b) {
                const int r = wc * 64 + b * 16 + l15;
                bg[b] = *(const short8*)(ldsBg + r * 64 + sl);
                bu[b] = *(const short8*)(ldsBu + r * 64 + sl);
            }
            #pragma unroll
            for (int a = 0; a < 4; ++a)
                #pragma unroll
                for (int b = 0; b < 4; ++b) {
                    accG[a][b] = __builtin_amdgcn_mfma_f32_16x16x32_bf16(af[kk][a], bg[b], accG[a][b], 0, 0, 0);
                    accU[a][b] = __builtin_amdgcn_mfma_f32_16x16x32_bf16(af[kk][a], bu[b], accU[a][b], 0, 0, 0);
                }
        }
    }

    // epilogue: silu(gate)*up -> bf16 hidden (in-wave)
    #pragma unroll
    for (int a = 0; a < 4; ++a)
        #pragma unroll
        for (int b = 0; b < 4; ++b)
            #pragma unroll
            for (int j = 0; j < 4; ++j) {
                const int row = m0 + wr * 64 + a * 16 + l4 * 4 + j;
                const int col = n0 + wc * 64 + b * 16 + l15;
                const float g = accG[a][b][j];
                const float u = accU[a][b][j];
                const float s = g / (1.0f + __expf(-g));
                hidden[(size_t)row * I_ + col] = f2bf(s * u);
            }
}

// ---------------------------------------------------------------------------
// GEMM2: out[T,H] fp32 = hidden(bf16) @ wdn_bf16^T. 128x128 tile, BK=64 over I.
// A (hidden) global->register; B staged (16 KiB LDS).
// ---------------------------------------------------------------------------
__global__ __launch_bounds__(256, 2) void k_gemm2(
    const unsigned short* __restrict__ hidden, const unsigned short* __restrict__ wdnb,
    float* __restrict__ out)
{
    __shared__ unsigned short lds[128 * 64];   // B only

    const int tid  = threadIdx.x;
    const int lane = tid & 63;
    const int wv   = tid >> 6;
    const int wr   = wv >> 1, wc = wv & 1;

    // XCD swizzle over 2048 blocks (2048 % 8 == 0)
    const int nb = (blockIdx.x & 7) * 256 + (blockIdx.x >> 3);
    const int bx = nb % 16, by = nb / 16;
    const int m0 = by * 128;
    const int n0 = bx * 128;

    f32x4 acc[4][4];
    #pragma unroll
    for (int a = 0; a < 4; ++a)
        #pragma unroll
        for (int b = 0; b < 4; ++b) acc[a][b] = (f32x4)0.0f;

    const int drow = lane >> 3;
    const int gcol = (((lane & 7) ^ drow) * 8);
    const int l15 = lane & 15;
    const int l4  = lane >> 4;
    const int sw  = l15 & 7;

    const unsigned short* aBase = hidden + (size_t)(m0 + wr * 64 + l15) * I_ + l4 * 8;

    for (int k0 = 0; k0 < I_; k0 += 64) {
        __syncthreads();
        short8 af[2][4];
        #pragma unroll
        for (int kk = 0; kk < 2; ++kk)
            #pragma unroll
            for (int a = 0; a < 4; ++a)
                af[kk][a] = *(const short8*)(aBase + (size_t)(a * 16) * I_ + k0 + kk * 32);
        #pragma unroll
        for (int r = 0; r < 4; ++r) {
            const int row  = r * 32 + wv * 8 + drow;
            const int loff = r * 2048 + wv * 512;
            gload16(wdnb + (size_t)(n0 + row) * I_ + k0 + gcol, lds + loff);
        }
        __syncthreads();

        #pragma unroll
        for (int kk = 0; kk < 2; ++kk) {
            const int sl = ((kk * 4 + l4) ^ sw) * 8;
            short8 bw[4];
            #pragma unroll
            for (int b = 0; b < 4; ++b) {
                const int r = wc * 64 + b * 16 + l15;
                bw[b] = *(const short8*)(lds + r * 64 + sl);
            }
            #pragma unroll
            for (int a = 0; a < 4; ++a)
                #pragma unroll
                for (int b = 0; b < 4; ++b)
                    acc[a][b] = __builtin_amdgcn_mfma_f32_16x16x32_bf16(af[kk][a], bw[b], acc[a][b], 0, 0, 0);
        }
    }

    #pragma unroll
    for (int a = 0; a < 4; ++a)
        #pragma unroll
        for (int b = 0; b < 4; ++b)
            #pragma unroll
            for (int j = 0; j < 4; ++j) {
                const int row = m0 + wr * 64 + a * 16 + l4 * 4 + j;
                const int col = n0 + wc * 64 + b * 16 + l15;
                out[(size_t)row * H_ + col] = acc[a][b][j];
            }
}

} // namespace

extern "C" void kernel_launch(void* const* d_in, const int* in_sizes, int n_in,
                              void* d_out, int out_size, void* d_ws, size_t ws_size,
                              hipStream_t stream) {
    const float* x   = (const float*)d_in[0];   // [T, H]
    const float* wgu = (const float*)d_in[1];   // [E, 2I, H]
    const float* wdn = (const float*)d_in[2];   // [E, H, I]
    const int* eidx  = (const int*)d_in[3];     // [1]
    float* out = (float*)d_out;                 // [T, H]

    // d_out (134.2 MB fp32) temporarily holds xb (67.1 MB) — dead before k_gemm2
    // overwrites it. ws: hidden | wgu_bf16 | wdn_bf16 = 69.2 MB.
    unsigned short* xb     = (unsigned short*)d_out;
    unsigned short* hidden = (unsigned short*)d_ws;
    unsigned short* wgub   = (unsigned short*)((char*)d_ws + 50331648);
    unsigned short* wdnb   = (unsigned short*)((char*)d_ws + 62914560);

    k_cvt_all<<<2048, 256, 0, stream>>>(x, wgu, wdn, eidx, xb, wgub, wdnb);
    k_gemm1_swiglu<<<dim3((I_ / 128) * (T_ / 128)), 256, 0, stream>>>(xb, wgub, hidden);
    k_gemm2<<<dim3((H_ / 128) * (T_ / 128)), 256, 0, stream>>>(hidden, wdnb, out);
}

// Round 13
// 337.425 us; speedup vs baseline: 1.4774x; 1.4774x over previous
//
#include <hip/hip_runtime.h>
#include <hip/hip_bf16.h>

// Glm4MoeExpertLayers: x[T,H] fp32, Wgu[E,2I,H] fp32, Wdn[E,H,I] fp32, expert_idx
//   gu = x @ Wgu[e]^T ; hidden = silu(gu[:, :I]) * gu[:, I:] ; out = hidden @ Wdn[e]^T
// T=16384 H=2048 I=1536.
// R13 = R10 GEMM1 (best known: 128^2 two-barrier, conflict-free swizzle, 3 blk/CU)
//     + GEMM2 single-barrier DOUBLE-BUFFER: 2x32KB LDS (2 blk/CU kept), loop =
//       {stage(t+1) -> compute(t) -> vmcnt(0 own) -> raw s_barrier} — one barrier
//       per K-tile, DMA of t+1 in flight during compute(t) (no drain stall).
// R12 lesson: global->reg A frags are uncoalesced (FETCH +82MB, util 31%) — LDS
// staging via gload_lds is mandatory for both operands.

namespace {

constexpr int T_ = 16384;
constexpr int H_ = 2048;
constexpr int I_ = 1536;

typedef short short8 __attribute__((ext_vector_type(8)));
typedef float f32x4 __attribute__((ext_vector_type(4)));
typedef unsigned short ushort4v __attribute__((ext_vector_type(4)));

__device__ __forceinline__ unsigned short f2bf(float f) {
    union { float f; unsigned u; } v; v.f = f;
    return (unsigned short)((v.u + 0x7FFFu + ((v.u >> 16) & 1u)) >> 16);
}

typedef __attribute__((address_space(1))) const void gvoid;
typedef __attribute__((address_space(3))) void lvoid;
__device__ __forceinline__ void gload16(const void* g, void* l) {
    __builtin_amdgcn_global_load_lds((gvoid*)g, (lvoid*)l, 16, 0, 0);
}

#define SBAR() do { __builtin_amdgcn_s_barrier(); __builtin_amdgcn_sched_barrier(0); } while (0)
#define VMCNT0() do { asm volatile("s_waitcnt vmcnt(0)" ::: "memory"); __builtin_amdgcn_sched_barrier(0); } while (0)

// ---------------------------------------------------------------------------
// fused fp32->bf16 conversion of x, Wgu[e], Wdn[e]
// ---------------------------------------------------------------------------
__global__ void k_cvt_all(const float* __restrict__ x, const float* __restrict__ wgu,
                          const float* __restrict__ wdn, const int* __restrict__ eidx,
                          unsigned short* __restrict__ xb, unsigned short* __restrict__ wgub,
                          unsigned short* __restrict__ wdnb) {
    const int e = *eidx;
    const int n1 = T_ * H_ / 4;
    const int n2 = 2 * I_ * H_ / 4;
    const int n3 = H_ * I_ / 4;
    const int ntot = n1 + n2 + n3;
    const float* wgu_e = wgu + (size_t)e * (size_t)(2 * I_) * H_;
    const float* wdn_e = wdn + (size_t)e * (size_t)H_ * I_;
    const int stride = gridDim.x * blockDim.x;
    for (int i = blockIdx.x * blockDim.x + threadIdx.x; i < ntot; i += stride) {
        const float* src; unsigned short* dst; int j;
        if (i < n1)           { src = x;     dst = xb;   j = i; }
        else if (i < n1 + n2) { src = wgu_e; dst = wgub; j = i - n1; }
        else                  { src = wdn_e; dst = wdnb; j = i - n1 - n2; }
        f32x4 v = ((const f32x4*)src)[j];
        ushort4v h = { f2bf(v[0]), f2bf(v[1]), f2bf(v[2]), f2bf(v[3]) };
        ((ushort4v*)dst)[j] = h;
    }
}

// ---------------------------------------------------------------------------
// GEMM1 + SwiGLU: hidden[T,I](bf16) = silu(xb@Wg^T) * (xb@Wu^T)
// R10-exact: 256 thr (4 waves 2x2), tile 128x128, BK=64, dual-B in-wave,
// two-barrier gload_lds staging, both-sides swizzle (slot ^= row&7). 48 KiB.
// ---------------------------------------------------------------------------
__global__ __launch_bounds__(256, 2) void k_gemm1_swiglu(
    const unsigned short* __restrict__ xb, const unsigned short* __restrict__ wgub,
    unsigned short* __restrict__ hidden)
{
    __shared__ unsigned short lds[3 * 128 * 64];
    unsigned short* ldsA  = lds;
    unsigned short* ldsBg = lds + 128 * 64;
    unsigned short* ldsBu = lds + 2 * 128 * 64;

    const int tid  = threadIdx.x;
    const int lane = tid & 63;
    const int wv   = tid >> 6;
    const int wr   = wv >> 1, wc = wv & 1;

    const int nb = (blockIdx.x & 7) * 192 + (blockIdx.x >> 3);
    const int bx = nb % 12, by = nb / 12;
    const int m0 = by * 128;
    const int n0 = bx * 128;

    f32x4 accG[4][4], accU[4][4];
    #pragma unroll
    for (int a = 0; a < 4; ++a)
        #pragma unroll
        for (int b = 0; b < 4; ++b) { accG[a][b] = (f32x4)0.0f; accU[a][b] = (f32x4)0.0f; }

    const int drow = lane >> 3;
    const int gcol = (((lane & 7) ^ drow) * 8);
    const int l15 = lane & 15;
    const int l4  = lane >> 4;
    const int sw  = l15 & 7;

    for (int k0 = 0; k0 < H_; k0 += 64) {
        __syncthreads();
        #pragma unroll
        for (int r = 0; r < 4; ++r) {
            const int row  = r * 32 + wv * 8 + drow;
            const int loff = r * 2048 + wv * 512;
            gload16(xb   + (size_t)(m0 + row)      * H_ + k0 + gcol, ldsA  + loff);
            gload16(wgub + (size_t)(n0 + row)      * H_ + k0 + gcol, ldsBg + loff);
            gload16(wgub + (size_t)(I_ + n0 + row) * H_ + k0 + gcol, ldsBu + loff);
        }
        __syncthreads();

        #pragma unroll
        for (int kk = 0; kk < 2; ++kk) {
            const int sl = ((kk * 4 + l4) ^ sw) * 8;
            short8 af[4], bg[4], bu[4];
            #pragma unroll
            for (int a = 0; a < 4; ++a) {
                const int r = wr * 64 + a * 16 + l15;
                af[a] = *(const short8*)(ldsA + r * 64 + sl);
            }
            #pragma unroll
            for (int b = 0; b < 4; ++b) {
                const int r = wc * 64 + b * 16 + l15;
                bg[b] = *(const short8*)(ldsBg + r * 64 + sl);
                bu[b] = *(const short8*)(ldsBu + r * 64 + sl);
            }
            #pragma unroll
            for (int a = 0; a < 4; ++a)
                #pragma unroll
                for (int b = 0; b < 4; ++b) {
                    accG[a][b] = __builtin_amdgcn_mfma_f32_16x16x32_bf16(af[a], bg[b], accG[a][b], 0, 0, 0);
                    accU[a][b] = __builtin_amdgcn_mfma_f32_16x16x32_bf16(af[a], bu[b], accU[a][b], 0, 0, 0);
                }
        }
    }

    #pragma unroll
    for (int a = 0; a < 4; ++a)
        #pragma unroll
        for (int b = 0; b < 4; ++b)
            #pragma unroll
            for (int j = 0; j < 4; ++j) {
                const int row = m0 + wr * 64 + a * 16 + l4 * 4 + j;
                const int col = n0 + wc * 64 + b * 16 + l15;
                const float g = accG[a][b][j];
                const float u = accU[a][b][j];
                const float s = g / (1.0f + __expf(-g));
                hidden[(size_t)row * I_ + col] = f2bf(s * u);
            }
}

// ---------------------------------------------------------------------------
// GEMM2: out[T,H] fp32 = hidden(bf16) @ wdn_bf16^T. 128x128 tile, BK=64 over I.
// Single-barrier double-buffer: 2 x (A 16K + B 16K) = 64 KiB -> 2 blocks/CU.
// Loop: stage(t+1) ; compute(t) ; vmcnt(0) ; s_barrier.  DMA overlaps compute.
// ---------------------------------------------------------------------------
__global__ __launch_bounds__(256, 2) void k_gemm2(
    const unsigned short* __restrict__ hidden, const unsigned short* __restrict__ wdnb,
    float* __restrict__ out)
{
    __shared__ unsigned short lds[2 * 2 * 128 * 64];   // buf0{A,B} buf1{A,B}

    const int tid  = threadIdx.x;
    const int lane = tid & 63;
    const int wv   = tid >> 6;
    const int wr   = wv >> 1, wc = wv & 1;

    const int nb = (blockIdx.x & 7) * 256 + (blockIdx.x >> 3);
    const int bx = nb % 16, by = nb / 16;
    const int m0 = by * 128;
    const int n0 = bx * 128;

    f32x4 acc[4][4];
    #pragma unroll
    for (int a = 0; a < 4; ++a)
        #pragma unroll
        for (int b = 0; b < 4; ++b) acc[a][b] = (f32x4)0.0f;

    const int drow = lane >> 3;
    const int gcol = (((lane & 7) ^ drow) * 8);
    const int l15 = lane & 15;
    const int l4  = lane >> 4;
    const int sw  = l15 & 7;

    constexpr int NT = I_ / 64;   // 24

    auto stage = [&](int t) {
        unsigned short* dA = lds + (t & 1) * 16384;
        unsigned short* dB = dA + 8192;
        const int kS = t * 64;
        #pragma unroll
        for (int r = 0; r < 4; ++r) {
            const int row  = r * 32 + wv * 8 + drow;
            const int loff = r * 2048 + wv * 512;
            gload16(hidden + (size_t)(m0 + row) * I_ + kS + gcol, dA + loff);
            gload16(wdnb   + (size_t)(n0 + row) * I_ + kS + gcol, dB + loff);
        }
    };

    stage(0);
    VMCNT0();
    SBAR();

    for (int t = 0; t < NT; ++t) {
        if (t + 1 < NT) stage(t + 1);          // DMA flies during compute(t)

        const unsigned short* bA = lds + (t & 1) * 16384;
        const unsigned short* bB = bA + 8192;
        #pragma unroll
        for (int kk = 0; kk < 2; ++kk) {
            const int sl = ((kk * 4 + l4) ^ sw) * 8;
            short8 af[4], bw[4];
            #pragma unroll
            for (int a = 0; a < 4; ++a) {
                const int r = wr * 64 + a * 16 + l15;
                af[a] = *(const short8*)(bA + r * 64 + sl);
            }
            #pragma unroll
            for (int b = 0; b < 4; ++b) {
                const int r = wc * 64 + b * 16 + l15;
                bw[b] = *(const short8*)(bB + r * 64 + sl);
            }
            #pragma unroll
            for (int a = 0; a < 4; ++a)
                #pragma unroll
                for (int b = 0; b < 4; ++b)
                    acc[a][b] = __builtin_amdgcn_mfma_f32_16x16x32_bf16(af[a], bw[b], acc[a][b], 0, 0, 0);
        }

        VMCNT0();   // own stage(t+1) loads: issued ~compute-duration ago -> cheap
        SBAR();     // all waves: done reading buf[t], own DMA drained
    }

    #pragma unroll
    for (int a = 0; a < 4; ++a)
        #pragma unroll
        for (int b = 0; b < 4; ++b)
            #pragma unroll
            for (int j = 0; j < 4; ++j) {
                const int row = m0 + wr * 64 + a * 16 + l4 * 4 + j;
                const int col = n0 + wc * 64 + b * 16 + l15;
                out[(size_t)row * H_ + col] = acc[a][b][j];
            }
}

} // namespace

extern "C" void kernel_launch(void* const* d_in, const int* in_sizes, int n_in,
                              void* d_out, int out_size, void* d_ws, size_t ws_size,
                              hipStream_t stream) {
    const float* x   = (const float*)d_in[0];   // [T, H]
    const float* wgu = (const float*)d_in[1];   // [E, 2I, H]
    const float* wdn = (const float*)d_in[2];   // [E, H, I]
    const int* eidx  = (const int*)d_in[3];     // [1]
    float* out = (float*)d_out;                 // [T, H]

    // d_out (134.2 MB fp32) temporarily holds xb (67.1 MB) — dead before k_gemm2
    // overwrites it. ws: hidden | wgu_bf16 | wdn_bf16 = 69.2 MB.
    unsigned short* xb     = (unsigned short*)d_out;
    unsigned short* hidden = (unsigned short*)d_ws;
    unsigned short* wgub   = (unsigned short*)((char*)d_ws + 50331648);
    unsigned short* wdnb   = (unsigned short*)((char*)d_ws + 62914560);

    k_cvt_all<<<2048, 256, 0, stream>>>(x, wgu, wdn, eidx, xb, wgub, wdnb);
    k_gemm1_swiglu<<<dim3((I_ / 128) * (T_ / 128)), 256, 0, stream>>>(xb, wgub, hidden);
    k_gemm2<<<dim3((H_ / 128) * (T_ / 128)), 256, 0, stream>>>(hidden, wdnb, out);
}